// Round 5
// baseline (101.025 us; speedup 1.0000x reference)
//
#include <hip/hip_runtime.h>

#define NROWS 2048
#define KDIM  768
#define L     40
#define KCH   6          // K-chunks per matrix (768 = 6 * 128)
#define KCSZ  128        // K per chunk
#define HN    (NROWS * L)   // 81920 floats per h matrix

// ---------------------------------------------------------------------------
// Kernel 1: partial projections, K split across blocks. 2 ROWS PER THREAD:
// W-chunk loads (the L1-bound part) are reused across 2 rows -> per-row
// VMEM instr count halved vs the 1-row version.
// Block 256 = 16 thread-rows x 16 segs; block covers 32 rows (r and r+16).
// Seg pairs pre-reduced in-register via shfl_xor(8) -> LDS stores 8 partials
// per (row,o) instead of 16. LDS 42KB -> 3 blocks/CU; grid 768 = 3/CU exact.
// ---------------------------------------------------------------------------
#define PSTR 328   // row stride in sh: 40*8 + 8 pad; 328%32==8 -> writes conflict-free

__global__ __launch_bounds__(256) void k_proj(const float* __restrict__ x,
                                              const float* __restrict__ y,
                                              const float* __restrict__ W1,
                                              float* __restrict__ part) {
    const int kc    = blockIdx.y;
    const int which = blockIdx.z;
    const float* __restrict__ A = which ? y : x;
    const int tid = threadIdx.x;
    const int r   = tid >> 4;    // 0..15 thread-row
    const int seg = tid & 15;    // 0..15 K-segment (8 floats each)
    const int row0 = blockIdx.x * 32;

    __shared__ float sh[32 * PSTR];   // [32 rows][40 o][8 segpairs(+pad)]

    const float* arowA = A + (size_t)(row0 + r) * KDIM + kc * KCSZ;
    const float* arowB = A + (size_t)(row0 + 16 + r) * KDIM + kc * KCSZ;
    float4 a0 = *(const float4*)(arowA + seg * 4);
    float4 a1 = *(const float4*)(arowA + 64 + seg * 4);
    float4 b0 = *(const float4*)(arowB + seg * 4);
    float4 b1 = *(const float4*)(arowB + 64 + seg * 4);

    const float* wbase = W1 + (size_t)which * KDIM + kc * KCSZ;
#pragma unroll 8
    for (int o = 0; o < L; ++o) {
        const float* wrow = wbase + (size_t)o * (2 * KDIM);
        float4 w0 = *(const float4*)(wrow + seg * 4);
        float4 w1 = *(const float4*)(wrow + 64 + seg * 4);
        float sA = a0.x * w0.x + a0.y * w0.y + a0.z * w0.z + a0.w * w0.w
                 + a1.x * w1.x + a1.y * w1.y + a1.z * w1.z + a1.w * w1.w;
        float sB = b0.x * w0.x + b0.y * w0.y + b0.z * w0.z + b0.w * w0.w
                 + b1.x * w1.x + b1.y * w1.y + b1.z * w1.z + b1.w * w1.w;
        sA += __shfl_xor(sA, 8);     // combine seg and seg^8 in-register
        sB += __shfl_xor(sB, 8);
        if (seg < 8) {
            sh[r * PSTR + o * 8 + seg] = sA;
            sh[(r + 16) * PSTR + o * 8 + seg] = sB;
        }
    }
    __syncthreads();

    // reduce 8 segpairs -> 32*40 outputs; one float4-pair per output
    float* pout = part + (size_t)(kc * 2 + which) * HN + (size_t)row0 * L;
#pragma unroll
    for (int k = 0; k < 5; ++k) {
        int idx = tid + k * 256;            // 0..1279
        int rr = idx / L;
        int o  = idx - rr * L;
        const float4* p = (const float4*)(sh + rr * PSTR + o * 8);
        float4 u0 = p[0], u1 = p[1];
        pout[idx] = u0.x + u0.y + u0.z + u0.w + u1.x + u1.y + u1.z + u1.w;
    }
}

// ---------------------------------------------------------------------------
// Kernel 1b: reduce the 6 K-chunk partials -> hxb (b1 folded in) and hy.
// ---------------------------------------------------------------------------
__global__ __launch_bounds__(256) void k_red(const float* __restrict__ part,
                                             const float* __restrict__ b1,
                                             float* __restrict__ hxb,
                                             float* __restrict__ hy) {
    int gid = blockIdx.x * 256 + threadIdx.x;   // 0 .. 2*HN-1
    int which = gid / HN;
    int rem   = gid - which * HN;
    float s = 0.f;
#pragma unroll
    for (int kc = 0; kc < KCH; ++kc)
        s += part[(size_t)(kc * 2 + which) * HN + rem];
    if (!which) {
        s += b1[rem % L];
        hxb[rem] = s;
    } else {
        hy[rem] = s;
    }
}

// ---------------------------------------------------------------------------
// Kernel 2: pairwise sum of exp(T_ij - 1) + diagonal T0 sum.
// Tile BI=128 x BJ=64, block 512 = 32(ty) x 16(tx), micro-tile 4x4.
// __launch_bounds__(512,4): cap 128 VGPR (R3's binary was 40 VGPR -> could
// not hold even one k4's fragments -> zero LDS-read pipelining, ~60% VALU).
// Explicit 2-deep double-buffered fragment pipeline, static register names.
// No atomics: per-block partials to pairE/pairT.
// ---------------------------------------------------------------------------
#define BI 128
#define BJ 64
#define STRD 44

__global__ __launch_bounds__(512, 4) void k_pair(const float* __restrict__ hxb,
                                                 const float* __restrict__ hy,
                                                 const float* __restrict__ W2,
                                                 const float* __restrict__ b2p,
                                                 float* __restrict__ pairE,
                                                 float* __restrict__ pairT) {
    __shared__ float shy[BI * STRD];
    __shared__ float shx[BJ * STRD];
    __shared__ float sw2[STRD];
    __shared__ float red[16];

    const int tid = threadIdx.x;
    const int i0 = blockIdx.x * BI;
    const int j0 = blockIdx.y * BJ;

    for (int idx = tid; idx < BI * 10; idx += 512) {
        int rr = idx / 10, c = idx - rr * 10;
        float4 v = ((const float4*)(hy + (size_t)i0 * L))[idx];
        *(float4*)(shy + rr * STRD + c * 4) = v;
    }
    for (int idx = tid; idx < BJ * 10; idx += 512) {
        int rr = idx / 10, c = idx - rr * 10;
        float4 v = ((const float4*)(hxb + (size_t)j0 * L))[idx];
        *(float4*)(shx + rr * STRD + c * 4) = v;
    }
    if (tid < 10) ((float4*)sw2)[tid] = ((const float4*)W2)[tid];
    __syncthreads();

    const int tx = tid & 15, ty = tid >> 4;   // ty 0..31

    float acc[4][4];
#pragma unroll
    for (int u = 0; u < 4; ++u)
#pragma unroll
        for (int v = 0; v < 4; ++v) acc[u][v] = 0.f;

    float4 ayA[4], axA[4], wA4;
    float4 ayB[4], axB[4], wB4;

#define LOADF(AY, AX, W4, K4) do {                                          \
    W4 = *(const float4*)(sw2 + (K4) * 4);                                  \
    _Pragma("unroll") for (int u_ = 0; u_ < 4; ++u_)                        \
        AY[u_] = *(const float4*)(shy + (ty + 32 * u_) * STRD + (K4) * 4);  \
    _Pragma("unroll") for (int v_ = 0; v_ < 4; ++v_)                        \
        AX[v_] = *(const float4*)(shx + (tx + 16 * v_) * STRD + (K4) * 4);  \
} while (0)

#define FMAF(AY, AX, W4) do {                                               \
    _Pragma("unroll") for (int u_ = 0; u_ < 4; ++u_)                        \
    _Pragma("unroll") for (int v_ = 0; v_ < 4; ++v_) {                      \
        float t;                                                            \
        t = AY[u_].x + AX[v_].x; t = fmaxf(t, 0.f); acc[u_][v_] += t * W4.x;\
        t = AY[u_].y + AX[v_].y; t = fmaxf(t, 0.f); acc[u_][v_] += t * W4.y;\
        t = AY[u_].z + AX[v_].z; t = fmaxf(t, 0.f); acc[u_][v_] += t * W4.z;\
        t = AY[u_].w + AX[v_].w; t = fmaxf(t, 0.f); acc[u_][v_] += t * W4.w;\
    }                                                                       \
} while (0)

    LOADF(ayA, axA, wA4, 0);
    LOADF(ayB, axB, wB4, 1);
    FMAF(ayA, axA, wA4); LOADF(ayA, axA, wA4, 2);
    FMAF(ayB, axB, wB4); LOADF(ayB, axB, wB4, 3);
    FMAF(ayA, axA, wA4); LOADF(ayA, axA, wA4, 4);
    FMAF(ayB, axB, wB4); LOADF(ayB, axB, wB4, 5);
    FMAF(ayA, axA, wA4); LOADF(ayA, axA, wA4, 6);
    FMAF(ayB, axB, wB4); LOADF(ayB, axB, wB4, 7);
    FMAF(ayA, axA, wA4); LOADF(ayA, axA, wA4, 8);
    FMAF(ayB, axB, wB4); LOADF(ayB, axB, wB4, 9);
    FMAF(ayA, axA, wA4);
    FMAF(ayB, axB, wB4);

#undef LOADF
#undef FMAF

    const float b2v = b2p[0];
    const float c1  = b2v - 1.f;
    float sumE = 0.f, sumT = 0.f;
#pragma unroll
    for (int u = 0; u < 4; ++u)
#pragma unroll
        for (int v = 0; v < 4; ++v) {
            int gi = i0 + ty + 32 * u;
            int gj = j0 + tx + 16 * v;
            float val = acc[u][v];
            if (gi == gj) sumT += val + b2v;
            sumE += __expf(val + c1);
        }

#pragma unroll
    for (int off = 32; off > 0; off >>= 1) {
        sumE += __shfl_down(sumE, off);
        sumT += __shfl_down(sumT, off);
    }
    int wid = tid >> 6;                     // 0..7
    if ((tid & 63) == 0) { red[wid] = sumE; red[8 + wid] = sumT; }
    __syncthreads();
    if (tid == 0) {
        float e = 0.f, t = 0.f;
#pragma unroll
        for (int q = 0; q < 8; ++q) { e += red[q]; t += red[8 + q]; }
        int bid = blockIdx.y * gridDim.x + blockIdx.x;   // 0..511
        pairE[bid] = e;
        pairT[bid] = t;
    }
}

// ---------------------------------------------------------------------------
// Kernel 3: reduce 512 block-partials -> lower_bound.
// ---------------------------------------------------------------------------
__global__ __launch_bounds__(512) void k_fin(const float* __restrict__ pairE,
                                             const float* __restrict__ pairT,
                                             float* __restrict__ out) {
    __shared__ float red[16];
    const int tid = threadIdx.x;
    float e = pairE[tid];
    float t = pairT[tid];
#pragma unroll
    for (int off = 32; off > 0; off >>= 1) {
        e += __shfl_down(e, off);
        t += __shfl_down(t, off);
    }
    int wid = tid >> 6;
    if ((tid & 63) == 0) { red[wid] = e; red[8 + wid] = t; }
    __syncthreads();
    if (tid == 0) {
        float se = 0.f, st = 0.f;
#pragma unroll
        for (int q = 0; q < 8; ++q) { se += red[q]; st += red[8 + q]; }
        const float invN = 1.0f / (float)NROWS;
        out[0] = st * invN - se * invN * invN;
    }
}

extern "C" void kernel_launch(void* const* d_in, const int* in_sizes, int n_in,
                              void* d_out, int out_size, void* d_ws, size_t ws_size,
                              hipStream_t stream) {
    const float* x  = (const float*)d_in[0];
    const float* y  = (const float*)d_in[1];
    const float* W1 = (const float*)d_in[2];
    const float* b1 = (const float*)d_in[3];
    const float* W2 = (const float*)d_in[4];
    const float* b2 = (const float*)d_in[5];
    float* out = (float*)d_out;

    float* wsf   = (float*)d_ws;
    float* hxb   = wsf;                  // 2048*40, b1 folded in
    float* hy    = hxb + HN;             // 2048*40
    float* part  = hy + HN;              // 6*2*2048*40 partials
    float* pairE = part + (size_t)KCH * 2 * HN;   // 512
    float* pairT = pairE + 512;                   // 512

    k_proj<<<dim3(NROWS / 32, KCH, 2), 256, 0, stream>>>(x, y, W1, part);
    k_red<<<(2 * HN) / 256, 256, 0, stream>>>(part, b1, hxb, hy);
    k_pair<<<dim3(NROWS / BI, NROWS / BJ), 512, 0, stream>>>(hxb, hy, W2, b2, pairE, pairT);
    k_fin<<<1, 512, 0, stream>>>(pairE, pairT, out);
}